// Round 1
// baseline (253.490 us; speedup 1.0000x reference)
//
#include <hip/hip_runtime.h>

// out[b, t, n, :] = x[b, (t - shift[n]) % 16, n, :]
// x: (B=16, T=16, N=196, c=768) fp32, contiguous.
//
// shift[n] closed form (m=1): w=n%7, h=n/7, a=w%3, b=h%3:
//   (0,0)->-4 (0,1)->1 (0,2)->2
//   (1,0)->-1 (1,1)-> (n==8 ? 0 : -1)   // sticky inv_state: only i=8 sees inv==0
//   (1,2)->3  (2,0)->-2 (2,1)->-3 (2,2)->4
//
// R3: split t across gridDim.z (4 t's per block).
//  - grid = 196*16*4 = 12544 blocks = exactly 49 blocks/CU (no tail imbalance;
//    previous 3136 blocks = 12.25/CU -> ~8% tail).
//  - live data shrinks f4 v[16] -> v[4] (64 -> 16 data VGPRs): more waves/SIMD,
//    shorter load->store windows that overlap across waves.
//  - 32-bit element indexing (max f4 index 9.6M < 2^31) to trim VALU addr work.

typedef float f4 __attribute__((ext_vector_type(4)));

__global__ __launch_bounds__(192) void Rand2dPatchShift_kernel(
        const f4* __restrict__ x, f4* __restrict__ out) {
    const int n  = blockIdx.x;      // 0..195
    const int b  = blockIdx.y;      // 0..15
    const int t0 = blockIdx.z * 4;  // 0,4,8,12

    const int w  = n % 7;
    const int h  = n / 7;
    const int a3 = w % 3;
    const int b3 = h % 3;

    int s;
    if (a3 == 0)      s = (b3 == 0) ? -4 : (b3 == 1 ? 1 : 2);
    else if (a3 == 1) s = (b3 == 0) ? -1 : (b3 == 1 ? ((n == 8) ? 0 : -1) : 3);
    else              s = (b3 == 0) ? -2 : (b3 == 1 ? -3 : 4);

    // element index (f4 units) of (b, t=0, n, threadIdx.x); t-stride = 196*192
    const int base    = (b * 3136 + n) * 192 + threadIdx.x;  // b*16*196 = b*3136
    const int tstride = 196 * 192;                           // 37632

    f4 v[4];
#pragma unroll
    for (int i = 0; i < 4; ++i) {
        const int tsrc = ((t0 + i) - s + 16) & 15;
        v[i] = __builtin_nontemporal_load(&x[base + tsrc * tstride]);
    }
#pragma unroll
    for (int i = 0; i < 4; ++i) {
        __builtin_nontemporal_store(v[i], &out[base + (t0 + i) * tstride]);
    }
}

extern "C" void kernel_launch(void* const* d_in, const int* in_sizes, int n_in,
                              void* d_out, int out_size, void* d_ws, size_t ws_size,
                              hipStream_t stream) {
    const f4* x = (const f4*)d_in[0];
    f4* out = (f4*)d_out;

    dim3 grid(196, 16, 4);  // (n, b, t-quarter) -> 12544 blocks = 49/CU exactly
    dim3 block(192);        // 3 waves, one float4 lane per thread, 4 t's each
    Rand2dPatchShift_kernel<<<grid, block, 0, stream>>>(x, out);
}